// Round 4
// baseline (1245.396 us; speedup 1.0000x reference)
//
#include <hip/hip_runtime.h>
#include <hip/hip_bf16.h>

#define N_NODES 100000
#define N_EDGES 1600000
#define N_PAIRS 500000
#define MPAD    100032   // 1563*64, 64-row padded node count
#define NF      128

typedef __bf16 bf16x8 __attribute__((ext_vector_type(8)));
typedef float  f32x4  __attribute__((ext_vector_type(4)));
typedef float  f32x2  __attribute__((ext_vector_type(2)));
typedef unsigned int       u32;
typedef unsigned short     u16;
typedef unsigned long long u64;

__device__ inline u16   f2b(float f) { __bf16 b = (__bf16)f; return __builtin_bit_cast(u16, b); }
__device__ inline float b2f(u16 u)   { return (float)__builtin_bit_cast(__bf16, u); }

// ---------- conversion kernels ----------
// dst is [N][K] bf16 (transposed), src is [K][N] f32
__global__ void k_convT(const float* __restrict__ src, u16* __restrict__ dst, int K, int N) {
    int i = blockIdx.x * 256 + threadIdx.x;
    if (i >= K * N) return;
    int n = i / K, k = i - n * K;
    dst[i] = f2b(src[k * N + n]);
}

// x f32 [N_NODES][128] -> packed bf16x2 [MPAD][64], pad rows zeroed
__global__ void k_convX(const f32x2* __restrict__ x, u32* __restrict__ xb) {
    int i = blockIdx.x * 256 + threadIdx.x;
    if (i >= MPAD * 64) return;
    int node = i >> 6;
    f32x2 v = {0.f, 0.f};
    if (node < N_NODES) v = __builtin_nontemporal_load(x + i);
    xb[i] = (u32)f2b(v.x) | ((u32)f2b(v.y) << 16);
}

// ---------- CSR build ----------
__global__ void k_hist(const int* __restrict__ row, int* __restrict__ deg) {
    int e = blockIdx.x * 256 + threadIdx.x;
    if (e >= N_EDGES) return;
    atomicAdd(&deg[row[e]], 1);
}

__global__ void k_scan1(const int* __restrict__ deg, int* __restrict__ incl, int* __restrict__ bsums) {
    __shared__ int s[1024];
    int t = threadIdx.x;
    int g = blockIdx.x * 1024 + t;
    s[t] = (g < N_NODES) ? deg[g] : 0;
    __syncthreads();
    for (int d = 1; d < 1024; d <<= 1) {
        int add = (t >= d) ? s[t - d] : 0;
        __syncthreads();
        s[t] += add;
        __syncthreads();
    }
    if (g < N_NODES) incl[g] = s[t];
    if (t == 1023) bsums[blockIdx.x] = s[1023];
}

__global__ void k_scan2(int* __restrict__ bsums, int nb) {
    __shared__ int s[128];
    int t = threadIdx.x;
    s[t] = (t < nb) ? bsums[t] : 0;
    __syncthreads();
    for (int d = 1; d < 128; d <<= 1) {
        int add = (t >= d) ? s[t - d] : 0;
        __syncthreads();
        s[t] += add;
        __syncthreads();
    }
    if (t < nb) bsums[t] = (t == 0) ? 0 : s[t - 1];
}

__global__ void k_scan3(const int* __restrict__ incl, const int* __restrict__ bsums,
                        int* __restrict__ rowptr, int* __restrict__ cursor) {
    int g = blockIdx.x * 256 + threadIdx.x;
    if (g == 0) { rowptr[0] = 0; cursor[0] = 0; }
    if (g >= N_NODES) return;
    int v = incl[g] + bsums[g >> 10];
    rowptr[g + 1] = v;
    if (g + 1 < N_NODES) cursor[g + 1] = v;
}

// packed edge record: low32 = col, high32 = f32 weight bits; single 8B store
__global__ void k_scatter(const int* __restrict__ row, const int* __restrict__ col,
                          const float* __restrict__ w, int* __restrict__ cursor,
                          u64* __restrict__ cce) {
    int e = blockIdx.x * 256 + threadIdx.x;
    if (e >= N_EDGES) return;
    int r = __builtin_nontemporal_load(row + e);
    int c = __builtin_nontemporal_load(col + e);
    float wv = __builtin_nontemporal_load(w + e);
    int pos = atomicAdd(&cursor[r], 1);
    cce[pos] = ((u64)__builtin_bit_cast(u32, wv) << 32) | (u32)c;
}

// ---------- fused dual GEMM: HSb = A@Ws (bf16), SUPc = A@Wn (bf16, chunk-major) ----------
// A: [MPAD][128] bf16 row-major; WsT/WnT: [128][128] bf16 (N-major, i.e. W^T)
// SUPc layout: [8 chunks][MPAD][16 feats] u16 -> per-edge gather is 32B from a 3.2MB chunk
__global__ void k_gemm_pair(const u16* __restrict__ A, const u16* __restrict__ WsT,
                            const u16* __restrict__ WnT, u16* __restrict__ HSb,
                            u16* __restrict__ SUPc) {
    int wid = threadIdx.x >> 6, lane = threadIdx.x & 63;
    int lr = lane & 15, lg = lane >> 4;
    int m0 = blockIdx.x * 64;
    const u16* WT = (wid < 2) ? WsT : WnT;
    int n0 = (wid & 1) * 64;
    f32x4 acc[4][4] = {};
    for (int ks = 0; ks < 4; ++ks) {
        int k0 = ks * 32 + lg * 8;
        bf16x8 a[4], b[4];
        #pragma unroll
        for (int r = 0; r < 4; ++r)
            a[r] = *reinterpret_cast<const bf16x8*>(A + (size_t)(m0 + r * 16 + lr) * NF + k0);
        #pragma unroll
        for (int c = 0; c < 4; ++c)
            b[c] = *reinterpret_cast<const bf16x8*>(WT + (size_t)(n0 + c * 16 + lr) * NF + k0);
        #pragma unroll
        for (int r = 0; r < 4; ++r)
            #pragma unroll
            for (int c = 0; c < 4; ++c)
                acc[r][c] = __builtin_amdgcn_mfma_f32_16x16x32_bf16(a[r], b[c], acc[r][c], 0, 0, 0);
    }
    #pragma unroll
    for (int r = 0; r < 4; ++r) {
        #pragma unroll
        for (int reg = 0; reg < 4; ++reg) {
            int m = m0 + r * 16 + lg * 4 + reg;
            if (m >= N_NODES) continue;
            #pragma unroll
            for (int c = 0; c < 4; ++c) {
                int col = n0 + c * 16 + lr;
                u16 v = f2b(acc[r][c][reg]);
                if (wid < 2) __builtin_nontemporal_store(v, HSb + (size_t)m * NF + col);
                else {
                    int ch = col >> 4, cc = col & 15;
                    SUPc[((size_t)ch * MPAD + m) * 16 + cc] = v;
                }
            }
        }
    }
}

// ---------- dual GEMM for decoder precompute: U = Z@W1a + b1, V = Z@W1b (both bf16, row-major) ----------
__global__ void k_gemm_uv(const u16* __restrict__ A, const u16* __restrict__ W1aT,
                          const u16* __restrict__ W1bT, const float* __restrict__ b1,
                          u16* __restrict__ U, u16* __restrict__ V) {
    int wid = threadIdx.x >> 6, lane = threadIdx.x & 63;
    int lr = lane & 15, lg = lane >> 4;
    int m0 = blockIdx.x * 64;
    const u16* WT = (wid < 2) ? W1aT : W1bT;
    u16* OUT = (wid < 2) ? U : V;
    int addb = (wid < 2) ? 1 : 0;
    int n0 = (wid & 1) * 64;
    f32x4 acc[4][4] = {};
    for (int ks = 0; ks < 4; ++ks) {
        int k0 = ks * 32 + lg * 8;
        bf16x8 a[4], b[4];
        #pragma unroll
        for (int r = 0; r < 4; ++r)
            a[r] = *reinterpret_cast<const bf16x8*>(A + (size_t)(m0 + r * 16 + lr) * NF + k0);
        #pragma unroll
        for (int c = 0; c < 4; ++c)
            b[c] = *reinterpret_cast<const bf16x8*>(WT + (size_t)(n0 + c * 16 + lr) * NF + k0);
        #pragma unroll
        for (int r = 0; r < 4; ++r)
            #pragma unroll
            for (int c = 0; c < 4; ++c)
                acc[r][c] = __builtin_amdgcn_mfma_f32_16x16x32_bf16(a[r], b[c], acc[r][c], 0, 0, 0);
    }
    #pragma unroll
    for (int r = 0; r < 4; ++r) {
        #pragma unroll
        for (int reg = 0; reg < 4; ++reg) {
            int m = m0 + r * 16 + lg * 4 + reg;
            #pragma unroll
            for (int c = 0; c < 4; ++c) {
                int col = n0 + c * 16 + lr;
                float v = acc[r][c][reg];
                if (addb) v += b1[col];
                OUT[(size_t)m * NF + col] = f2b(v);
            }
        }
    }
}

// ---------- aggregation (chunked): out = (relu?)(HS + sum_e w_e * SUP[col_e] + bias) ----------
// chunk = blockIdx % 8 -> pins each 3.2MB SUP chunk to one XCD's L2 (round-robin dispatch).
// Streams (edge records, HS) use non-temporal loads so they don't evict the SUP chunk.
// 8-lane subgroup per node per chunk; lane covers 2 features (1 u32).
__global__ void k_aggregate_c(const u32* __restrict__ SUPc, const u32* __restrict__ HSb,
                              const int* __restrict__ rowptr, const u64* __restrict__ cce,
                              const f32x2* __restrict__ bias2,
                              u32* __restrict__ Hout, f32x2* __restrict__ Zout, int relu) {
    int chunk = blockIdx.x & 7;
    int nb = blockIdx.x >> 3;
    int l = threadIdx.x & 63, w = threadIdx.x >> 6;
    int sub = l >> 3, sl = l & 7;
    int node = nb * 32 + w * 8 + sub;
    if (node >= N_NODES) return;
    const u32* base = SUPc + (size_t)chunk * MPAD * 8;
    int e0 = rowptr[node], e1 = rowptr[node + 1];
    float a0 = 0.f, a1 = 0.f;
    int e = e0;
    for (; e + 8 <= e1; e += 8) {
        u64 r[8];
        u32 v[8];
        #pragma unroll
        for (int i = 0; i < 8; ++i) r[i] = __builtin_nontemporal_load(cce + e + i);
        #pragma unroll
        for (int i = 0; i < 8; ++i) v[i] = base[(size_t)(u32)r[i] * 8 + sl];
        #pragma unroll
        for (int i = 0; i < 8; ++i) {
            float wt = __builtin_bit_cast(float, (u32)(r[i] >> 32));
            a0 = fmaf(wt, b2f((u16)(v[i] & 0xffff)), a0);
            a1 = fmaf(wt, b2f((u16)(v[i] >> 16)), a1);
        }
    }
    for (; e < e1; ++e) {
        u64 rr = __builtin_nontemporal_load(cce + e);
        u32 v = base[(size_t)(u32)rr * 8 + sl];
        float wt = __builtin_bit_cast(float, (u32)(rr >> 32));
        a0 = fmaf(wt, b2f((u16)(v & 0xffff)), a0);
        a1 = fmaf(wt, b2f((u16)(v >> 16)), a1);
    }
    size_t oidx = (size_t)node * 64 + chunk * 8 + sl;
    u32 hsv = __builtin_nontemporal_load(HSb + oidx);
    f32x2 bv = bias2[chunk * 8 + sl];
    float o0 = b2f((u16)(hsv & 0xffff)) + a0 + bv.x;
    float o1 = b2f((u16)(hsv >> 16)) + a1 + bv.y;
    if (relu) { o0 = fmaxf(o0, 0.f); o1 = fmaxf(o1, 0.f); }
    __builtin_nontemporal_store((u32)f2b(o0) | ((u32)f2b(o1) << 16), Hout + oidx);
    if (Zout) {
        f32x2 z = {o0, o1};
        __builtin_nontemporal_store(z, Zout + oidx);
    }
}

// ---------- pair decoder: p = sigmoid( sum_f relu(U[xi][f]+V[yi][f]) * w2[f] + b2 ) ----------
// 4 lanes per pair; lane j covers features [j*32, j*32+32)
__global__ void k_pairdec(const u16* __restrict__ U, const u16* __restrict__ V,
                          const int* __restrict__ xidx, const int* __restrict__ yidx,
                          const float* __restrict__ w2, const float* __restrict__ b2,
                          float* __restrict__ outp) {
    int t = blockIdx.x * 256 + threadIdx.x;
    int pair = t >> 2;
    int j = t & 3;
    if (pair >= N_PAIRS) return;
    int xi = __builtin_nontemporal_load(xidx + pair);
    int yi = __builtin_nontemporal_load(yidx + pair);
    const bf16x8* up = reinterpret_cast<const bf16x8*>(U + (size_t)xi * NF + j * 32);
    const bf16x8* vp = reinterpret_cast<const bf16x8*>(V + (size_t)yi * NF + j * 32);
    bf16x8 uu[4], vv[4];
    #pragma unroll
    for (int it = 0; it < 4; ++it) { uu[it] = up[it]; vv[it] = vp[it]; }
    const float4* w4 = reinterpret_cast<const float4*>(w2 + j * 32);
    float acc = 0.f;
    #pragma unroll
    for (int it = 0; it < 4; ++it) {
        float4 wa = w4[it * 2], wb = w4[it * 2 + 1];
        float h;
        h = fmaxf((float)uu[it][0] + (float)vv[it][0], 0.f); acc = fmaf(h, wa.x, acc);
        h = fmaxf((float)uu[it][1] + (float)vv[it][1], 0.f); acc = fmaf(h, wa.y, acc);
        h = fmaxf((float)uu[it][2] + (float)vv[it][2], 0.f); acc = fmaf(h, wa.z, acc);
        h = fmaxf((float)uu[it][3] + (float)vv[it][3], 0.f); acc = fmaf(h, wa.w, acc);
        h = fmaxf((float)uu[it][4] + (float)vv[it][4], 0.f); acc = fmaf(h, wb.x, acc);
        h = fmaxf((float)uu[it][5] + (float)vv[it][5], 0.f); acc = fmaf(h, wb.y, acc);
        h = fmaxf((float)uu[it][6] + (float)vv[it][6], 0.f); acc = fmaf(h, wb.z, acc);
        h = fmaxf((float)uu[it][7] + (float)vv[it][7], 0.f); acc = fmaf(h, wb.w, acc);
    }
    acc += __shfl_xor(acc, 1, 64);
    acc += __shfl_xor(acc, 2, 64);
    if (j == 0) outp[pair] = 1.f / (1.f + __expf(-(acc + b2[0])));
}

extern "C" void kernel_launch(void* const* d_in, const int* in_sizes, int n_in,
                              void* d_out, int out_size, void* d_ws, size_t ws_size,
                              hipStream_t stream) {
    const float* x      = (const float*)d_in[0];
    const int* edge_row = (const int*)d_in[1];
    const int* edge_col = (const int*)d_in[2];
    const float* edge_w = (const float*)d_in[3];
    const int* x_idx    = (const int*)d_in[4];
    const int* y_idx    = (const int*)d_in[5];
    const float* gws[3] = {(const float*)d_in[6], (const float*)d_in[9],  (const float*)d_in[12]};
    const float* gwn[3] = {(const float*)d_in[7], (const float*)d_in[10], (const float*)d_in[13]};
    const float* gb[3]  = {(const float*)d_in[8], (const float*)d_in[11], (const float*)d_in[14]};
    const float* dw1 = (const float*)d_in[15];
    const float* db1 = (const float*)d_in[16];
    const float* dw2 = (const float*)d_in[17];
    const float* db2 = (const float*)d_in[18];
    float* out_p = (float*)d_out;        // [N_PAIRS]
    float* out_z = out_p + N_PAIRS;      // [N_NODES*128]

    char* base = (char*)d_ws;
    size_t off = 0;
    auto alloc = [&](size_t bytes) -> void* {
        void* p = base + off;
        off = (off + bytes + 255) & ~(size_t)255;
        return p;
    };
    u16* h0   = (u16*)alloc((size_t)MPAD * NF * 2);
    u16* h1   = (u16*)alloc((size_t)MPAD * NF * 2);
    u16* supc = (u16*)alloc((size_t)MPAD * NF * 2);
    u16* hsb  = (u16*)alloc((size_t)MPAD * NF * 4);  // bf16 HS; U,V alias this later
    u16* wT[6];
    for (int i = 0; i < 6; ++i) wT[i] = (u16*)alloc(128 * 128 * 2);
    u16* w1aT = (u16*)alloc(128 * 128 * 2);
    u16* w1bT = (u16*)alloc(128 * 128 * 2);
    int* deg    = (int*)alloc(N_NODES * 4);
    int* incl   = (int*)alloc(N_NODES * 4);
    int* bsums  = (int*)alloc(128 * 4);
    int* rowptr = (int*)alloc((N_NODES + 1) * 4);
    int* cursor = (int*)alloc(N_NODES * 4);
    u64* cce    = (u64*)alloc((size_t)N_EDGES * 8);
    // U,V alias the hsb buffer (free after the last aggregate reads it)
    u16* U = hsb;
    u16* V = U + (size_t)MPAD * NF;

    (void)hipMemsetAsync(deg, 0, N_NODES * 4, stream);

    // weight conversion (transposed to [N][K] bf16)
    for (int l = 0; l < 3; ++l) {
        k_convT<<<64, 256, 0, stream>>>(gws[l], wT[2 * l],     128, 128);
        k_convT<<<64, 256, 0, stream>>>(gwn[l], wT[2 * l + 1], 128, 128);
    }
    k_convT<<<64, 256, 0, stream>>>(dw1,             w1aT, 128, 128);
    k_convT<<<64, 256, 0, stream>>>(dw1 + 128 * 128, w1bT, 128, 128);
    k_convX<<<(MPAD * 64 + 255) / 256, 256, 0, stream>>>((const f32x2*)x, (u32*)h0);

    // CSR build
    k_hist<<<(N_EDGES + 255) / 256, 256, 0, stream>>>(edge_row, deg);
    k_scan1<<<98, 1024, 0, stream>>>(deg, incl, bsums);
    k_scan2<<<1, 128, 0, stream>>>(bsums, 98);
    k_scan3<<<(N_NODES + 255) / 256, 256, 0, stream>>>(incl, bsums, rowptr, cursor);
    k_scatter<<<(N_EDGES + 255) / 256, 256, 0, stream>>>(edge_row, edge_col, edge_w, cursor, cce);

    const int GB = MPAD / 64;                  // 1563
    const int AB = 8 * ((N_NODES + 31) / 32);  // 8 chunks * 3125 nodeblocks

    // layer 1: x -> h1
    k_gemm_pair<<<GB, 256, 0, stream>>>(h0, wT[0], wT[1], hsb, supc);
    k_aggregate_c<<<AB, 256, 0, stream>>>((const u32*)supc, (const u32*)hsb, rowptr, cce,
                                          (const f32x2*)gb[0], (u32*)h1, nullptr, 1);
    // layer 2: h1 -> h0
    k_gemm_pair<<<GB, 256, 0, stream>>>(h1, wT[2], wT[3], hsb, supc);
    k_aggregate_c<<<AB, 256, 0, stream>>>((const u32*)supc, (const u32*)hsb, rowptr, cce,
                                          (const f32x2*)gb[1], (u32*)h0, nullptr, 1);
    // layer 3: h0 -> h1 (=z bf16) + z f32 to d_out
    k_gemm_pair<<<GB, 256, 0, stream>>>(h0, wT[4], wT[5], hsb, supc);
    k_aggregate_c<<<AB, 256, 0, stream>>>((const u32*)supc, (const u32*)hsb, rowptr, cce,
                                          (const f32x2*)gb[2], (u32*)h1, (f32x2*)out_z, 0);
    // decoder precompute: U = z@W1a + b1, V = z@W1b  (into the freed hsb region)
    k_gemm_uv<<<GB, 256, 0, stream>>>(h1, w1aT, w1bT, db1, U, V);
    // pair decoder
    k_pairdec<<<(N_PAIRS * 4 + 255) / 256, 256, 0, stream>>>(U, V, x_idx, y_idx, dw2, db2, out_p);
}

// Round 5
// 964.958 us; speedup vs baseline: 1.2906x; 1.2906x over previous
//
#include <hip/hip_runtime.h>
#include <hip/hip_bf16.h>

#define N_NODES 100000
#define N_EDGES 1600000
#define N_PAIRS 500000
#define MPAD    100032   // 1563*64, 64-row padded node count
#define NF      128

typedef __bf16 bf16x8 __attribute__((ext_vector_type(8)));
typedef float  f32x4  __attribute__((ext_vector_type(4)));
typedef float  f32x2  __attribute__((ext_vector_type(2)));
typedef unsigned int       u32;
typedef unsigned short     u16;
typedef unsigned long long u64;

__device__ inline u16   f2b(float f) { __bf16 b = (__bf16)f; return __builtin_bit_cast(u16, b); }
__device__ inline float b2f(u16 u)   { return (float)__builtin_bit_cast(__bf16, u); }
// decode 15-bit (sign-less) fp16 weight
__device__ inline float h2f(u16 u)   { return (float)__builtin_bit_cast(_Float16, u); }

// ---------- conversion kernels ----------
// dst is [N][K] bf16 (transposed), src is [K][N] f32
__global__ void k_convT(const float* __restrict__ src, u16* __restrict__ dst, int K, int N) {
    int i = blockIdx.x * 256 + threadIdx.x;
    if (i >= K * N) return;
    int n = i / K, k = i - n * K;
    dst[i] = f2b(src[k * N + n]);
}

// x f32 [N_NODES][128] -> packed bf16x2 [MPAD][64], pad rows zeroed
__global__ void k_convX(const f32x2* __restrict__ x, u32* __restrict__ xb) {
    int i = blockIdx.x * 256 + threadIdx.x;
    if (i >= MPAD * 64) return;
    int node = i >> 6;
    f32x2 v = {0.f, 0.f};
    if (node < N_NODES) v = __builtin_nontemporal_load(x + i);
    xb[i] = (u32)f2b(v.x) | ((u32)f2b(v.y) << 16);
}

// ---------- CSR build ----------
__global__ void k_hist(const int* __restrict__ row, int* __restrict__ deg) {
    int e = blockIdx.x * 256 + threadIdx.x;
    if (e >= N_EDGES) return;
    atomicAdd(&deg[row[e]], 1);
}

__global__ void k_scan1(const int* __restrict__ deg, int* __restrict__ incl, int* __restrict__ bsums) {
    __shared__ int s[1024];
    int t = threadIdx.x;
    int g = blockIdx.x * 1024 + t;
    s[t] = (g < N_NODES) ? deg[g] : 0;
    __syncthreads();
    for (int d = 1; d < 1024; d <<= 1) {
        int add = (t >= d) ? s[t - d] : 0;
        __syncthreads();
        s[t] += add;
        __syncthreads();
    }
    if (g < N_NODES) incl[g] = s[t];
    if (t == 1023) bsums[blockIdx.x] = s[1023];
}

__global__ void k_scan2(int* __restrict__ bsums, int nb) {
    __shared__ int s[128];
    int t = threadIdx.x;
    s[t] = (t < nb) ? bsums[t] : 0;
    __syncthreads();
    for (int d = 1; d < 128; d <<= 1) {
        int add = (t >= d) ? s[t - d] : 0;
        __syncthreads();
        s[t] += add;
        __syncthreads();
    }
    if (t < nb) bsums[t] = (t == 0) ? 0 : s[t - 1];
}

__global__ void k_scan3(const int* __restrict__ incl, const int* __restrict__ bsums,
                        int* __restrict__ rowptr, int* __restrict__ cursor) {
    int g = blockIdx.x * 256 + threadIdx.x;
    if (g == 0) { rowptr[0] = 0; cursor[0] = 0; }
    if (g >= N_NODES) return;
    int v = incl[g] + bsums[g >> 10];
    rowptr[g + 1] = v;
    if (g + 1 < N_NODES) cursor[g + 1] = v;
}

// packed edge record: (col << 15) | fp16(weight) low-15-bits; single 4B store.
// col < 2^17 (N_NODES=100000), weight in [0,1) so fp16 sign bit is 0.
__global__ void k_scatter(const int* __restrict__ row, const int* __restrict__ col,
                          const float* __restrict__ w, int* __restrict__ cursor,
                          u32* __restrict__ cce) {
    int e = blockIdx.x * 256 + threadIdx.x;
    if (e >= N_EDGES) return;
    int r = row[e];
    int c = col[e];
    float wv = w[e];
    _Float16 hw = (_Float16)wv;
    u32 rec = ((u32)c << 15) | (u32)__builtin_bit_cast(u16, hw);
    int pos = atomicAdd(&cursor[r], 1);
    cce[pos] = rec;
}

// ---------- fused dual GEMM: HSb = A@Ws (bf16), SUPc = A@Wn (bf16, chunk-major) ----------
// A: [MPAD][128] bf16 row-major; WsT/WnT: [128][128] bf16 (N-major, i.e. W^T)
// SUPc layout: [8 chunks][MPAD][16 feats] u16 -> per-edge gather is 32B from a 3.2MB chunk
__global__ void k_gemm_pair(const u16* __restrict__ A, const u16* __restrict__ WsT,
                            const u16* __restrict__ WnT, u16* __restrict__ HSb,
                            u16* __restrict__ SUPc) {
    int wid = threadIdx.x >> 6, lane = threadIdx.x & 63;
    int lr = lane & 15, lg = lane >> 4;
    int m0 = blockIdx.x * 64;
    const u16* WT = (wid < 2) ? WsT : WnT;
    int n0 = (wid & 1) * 64;
    f32x4 acc[4][4] = {};
    for (int ks = 0; ks < 4; ++ks) {
        int k0 = ks * 32 + lg * 8;
        bf16x8 a[4], b[4];
        #pragma unroll
        for (int r = 0; r < 4; ++r)
            a[r] = *reinterpret_cast<const bf16x8*>(A + (size_t)(m0 + r * 16 + lr) * NF + k0);
        #pragma unroll
        for (int c = 0; c < 4; ++c)
            b[c] = *reinterpret_cast<const bf16x8*>(WT + (size_t)(n0 + c * 16 + lr) * NF + k0);
        #pragma unroll
        for (int r = 0; r < 4; ++r)
            #pragma unroll
            for (int c = 0; c < 4; ++c)
                acc[r][c] = __builtin_amdgcn_mfma_f32_16x16x32_bf16(a[r], b[c], acc[r][c], 0, 0, 0);
    }
    #pragma unroll
    for (int r = 0; r < 4; ++r) {
        #pragma unroll
        for (int reg = 0; reg < 4; ++reg) {
            int m = m0 + r * 16 + lg * 4 + reg;
            if (m >= N_NODES) continue;
            #pragma unroll
            for (int c = 0; c < 4; ++c) {
                int col = n0 + c * 16 + lr;
                u16 v = f2b(acc[r][c][reg]);
                if (wid < 2) __builtin_nontemporal_store(v, HSb + (size_t)m * NF + col);
                else {
                    int ch = col >> 4, cc = col & 15;
                    SUPc[((size_t)ch * MPAD + m) * 16 + cc] = v;
                }
            }
        }
    }
}

// ---------- dual GEMM for decoder precompute: U = Z@W1a + b1, V = Z@W1b (both bf16, row-major) ----------
__global__ void k_gemm_uv(const u16* __restrict__ A, const u16* __restrict__ W1aT,
                          const u16* __restrict__ W1bT, const float* __restrict__ b1,
                          u16* __restrict__ U, u16* __restrict__ V) {
    int wid = threadIdx.x >> 6, lane = threadIdx.x & 63;
    int lr = lane & 15, lg = lane >> 4;
    int m0 = blockIdx.x * 64;
    const u16* WT = (wid < 2) ? W1aT : W1bT;
    u16* OUT = (wid < 2) ? U : V;
    int addb = (wid < 2) ? 1 : 0;
    int n0 = (wid & 1) * 64;
    f32x4 acc[4][4] = {};
    for (int ks = 0; ks < 4; ++ks) {
        int k0 = ks * 32 + lg * 8;
        bf16x8 a[4], b[4];
        #pragma unroll
        for (int r = 0; r < 4; ++r)
            a[r] = *reinterpret_cast<const bf16x8*>(A + (size_t)(m0 + r * 16 + lr) * NF + k0);
        #pragma unroll
        for (int c = 0; c < 4; ++c)
            b[c] = *reinterpret_cast<const bf16x8*>(WT + (size_t)(n0 + c * 16 + lr) * NF + k0);
        #pragma unroll
        for (int r = 0; r < 4; ++r)
            #pragma unroll
            for (int c = 0; c < 4; ++c)
                acc[r][c] = __builtin_amdgcn_mfma_f32_16x16x32_bf16(a[r], b[c], acc[r][c], 0, 0, 0);
    }
    #pragma unroll
    for (int r = 0; r < 4; ++r) {
        #pragma unroll
        for (int reg = 0; reg < 4; ++reg) {
            int m = m0 + r * 16 + lg * 4 + reg;
            #pragma unroll
            for (int c = 0; c < 4; ++c) {
                int col = n0 + c * 16 + lr;
                float v = acc[r][c][reg];
                if (addb) v += b1[col];
                OUT[(size_t)m * NF + col] = f2b(v);
            }
        }
    }
}

// ---------- aggregation (chunked): out = (relu?)(HS + sum_e w_e * SUP[col_e] + bias) ----------
// chunk = blockIdx % 8 -> pins each 3.2MB SUP chunk to one XCD's L2 (round-robin dispatch).
// Edge stream uses PLAIN loads (L2/L3-cached; nt loads here were a 2x regression — latency-bound).
// 8-lane subgroup per node per chunk; lane covers 2 features (1 u32).
__global__ void k_aggregate_c(const u32* __restrict__ SUPc, const u32* __restrict__ HSb,
                              const int* __restrict__ rowptr, const u32* __restrict__ cce,
                              const f32x2* __restrict__ bias2,
                              u32* __restrict__ Hout, f32x2* __restrict__ Zout, int relu) {
    int chunk = blockIdx.x & 7;
    int nb = blockIdx.x >> 3;
    int l = threadIdx.x & 63, w = threadIdx.x >> 6;
    int sub = l >> 3, sl = l & 7;
    int node = nb * 32 + w * 8 + sub;
    if (node >= N_NODES) return;
    const u32* base = SUPc + (size_t)chunk * MPAD * 8;
    int e0 = rowptr[node], e1 = rowptr[node + 1];
    float a0 = 0.f, a1 = 0.f;
    int e = e0;
    for (; e + 8 <= e1; e += 8) {
        u32 r[8];
        u32 v[8];
        #pragma unroll
        for (int i = 0; i < 8; ++i) r[i] = cce[e + i];
        #pragma unroll
        for (int i = 0; i < 8; ++i) v[i] = base[(size_t)(r[i] >> 15) * 8 + sl];
        #pragma unroll
        for (int i = 0; i < 8; ++i) {
            float wt = h2f((u16)(r[i] & 0x7fff));
            a0 = fmaf(wt, b2f((u16)(v[i] & 0xffff)), a0);
            a1 = fmaf(wt, b2f((u16)(v[i] >> 16)), a1);
        }
    }
    for (; e < e1; ++e) {
        u32 rr = cce[e];
        u32 v = base[(size_t)(rr >> 15) * 8 + sl];
        float wt = h2f((u16)(rr & 0x7fff));
        a0 = fmaf(wt, b2f((u16)(v & 0xffff)), a0);
        a1 = fmaf(wt, b2f((u16)(v >> 16)), a1);
    }
    size_t oidx = (size_t)node * 64 + chunk * 8 + sl;
    u32 hsv = __builtin_nontemporal_load(HSb + oidx);
    f32x2 bv = bias2[chunk * 8 + sl];
    float o0 = b2f((u16)(hsv & 0xffff)) + a0 + bv.x;
    float o1 = b2f((u16)(hsv >> 16)) + a1 + bv.y;
    if (relu) { o0 = fmaxf(o0, 0.f); o1 = fmaxf(o1, 0.f); }
    __builtin_nontemporal_store((u32)f2b(o0) | ((u32)f2b(o1) << 16), Hout + oidx);
    if (Zout) {
        f32x2 z = {o0, o1};
        __builtin_nontemporal_store(z, Zout + oidx);
    }
}

// ---------- pair decoder: p = sigmoid( sum_f relu(U[xi][f]+V[yi][f]) * w2[f] + b2 ) ----------
// 4 lanes per pair; lane j covers features [j*32, j*32+32)
__global__ void k_pairdec(const u16* __restrict__ U, const u16* __restrict__ V,
                          const int* __restrict__ xidx, const int* __restrict__ yidx,
                          const float* __restrict__ w2, const float* __restrict__ b2,
                          float* __restrict__ outp) {
    int t = blockIdx.x * 256 + threadIdx.x;
    int pair = t >> 2;
    int j = t & 3;
    if (pair >= N_PAIRS) return;
    int xi = xidx[pair];
    int yi = yidx[pair];
    const bf16x8* up = reinterpret_cast<const bf16x8*>(U + (size_t)xi * NF + j * 32);
    const bf16x8* vp = reinterpret_cast<const bf16x8*>(V + (size_t)yi * NF + j * 32);
    bf16x8 uu[4], vv[4];
    #pragma unroll
    for (int it = 0; it < 4; ++it) { uu[it] = up[it]; vv[it] = vp[it]; }
    const float4* w4 = reinterpret_cast<const float4*>(w2 + j * 32);
    float acc = 0.f;
    #pragma unroll
    for (int it = 0; it < 4; ++it) {
        float4 wa = w4[it * 2], wb = w4[it * 2 + 1];
        float h;
        h = fmaxf((float)uu[it][0] + (float)vv[it][0], 0.f); acc = fmaf(h, wa.x, acc);
        h = fmaxf((float)uu[it][1] + (float)vv[it][1], 0.f); acc = fmaf(h, wa.y, acc);
        h = fmaxf((float)uu[it][2] + (float)vv[it][2], 0.f); acc = fmaf(h, wa.z, acc);
        h = fmaxf((float)uu[it][3] + (float)vv[it][3], 0.f); acc = fmaf(h, wa.w, acc);
        h = fmaxf((float)uu[it][4] + (float)vv[it][4], 0.f); acc = fmaf(h, wb.x, acc);
        h = fmaxf((float)uu[it][5] + (float)vv[it][5], 0.f); acc = fmaf(h, wb.y, acc);
        h = fmaxf((float)uu[it][6] + (float)vv[it][6], 0.f); acc = fmaf(h, wb.z, acc);
        h = fmaxf((float)uu[it][7] + (float)vv[it][7], 0.f); acc = fmaf(h, wb.w, acc);
    }
    acc += __shfl_xor(acc, 1, 64);
    acc += __shfl_xor(acc, 2, 64);
    if (j == 0) outp[pair] = 1.f / (1.f + __expf(-(acc + b2[0])));
}

extern "C" void kernel_launch(void* const* d_in, const int* in_sizes, int n_in,
                              void* d_out, int out_size, void* d_ws, size_t ws_size,
                              hipStream_t stream) {
    const float* x      = (const float*)d_in[0];
    const int* edge_row = (const int*)d_in[1];
    const int* edge_col = (const int*)d_in[2];
    const float* edge_w = (const float*)d_in[3];
    const int* x_idx    = (const int*)d_in[4];
    const int* y_idx    = (const int*)d_in[5];
    const float* gws[3] = {(const float*)d_in[6], (const float*)d_in[9],  (const float*)d_in[12]};
    const float* gwn[3] = {(const float*)d_in[7], (const float*)d_in[10], (const float*)d_in[13]};
    const float* gb[3]  = {(const float*)d_in[8], (const float*)d_in[11], (const float*)d_in[14]};
    const float* dw1 = (const float*)d_in[15];
    const float* db1 = (const float*)d_in[16];
    const float* dw2 = (const float*)d_in[17];
    const float* db2 = (const float*)d_in[18];
    float* out_p = (float*)d_out;        // [N_PAIRS]
    float* out_z = out_p + N_PAIRS;      // [N_NODES*128]

    char* base = (char*)d_ws;
    size_t off = 0;
    auto alloc = [&](size_t bytes) -> void* {
        void* p = base + off;
        off = (off + bytes + 255) & ~(size_t)255;
        return p;
    };
    u16* h0   = (u16*)alloc((size_t)MPAD * NF * 2);
    u16* h1   = (u16*)alloc((size_t)MPAD * NF * 2);
    u16* supc = (u16*)alloc((size_t)MPAD * NF * 2);
    u16* hsb  = (u16*)alloc((size_t)MPAD * NF * 4);  // bf16 HS; U,V alias this later
    u16* wT[6];
    for (int i = 0; i < 6; ++i) wT[i] = (u16*)alloc(128 * 128 * 2);
    u16* w1aT = (u16*)alloc(128 * 128 * 2);
    u16* w1bT = (u16*)alloc(128 * 128 * 2);
    int* deg    = (int*)alloc(N_NODES * 4);
    int* incl   = (int*)alloc(N_NODES * 4);
    int* bsums  = (int*)alloc(128 * 4);
    int* rowptr = (int*)alloc((N_NODES + 1) * 4);
    int* cursor = (int*)alloc(N_NODES * 4);
    u32* cce    = (u32*)alloc((size_t)N_EDGES * 4);
    // U,V alias the hsb buffer (free after the last aggregate reads it)
    u16* U = hsb;
    u16* V = U + (size_t)MPAD * NF;

    (void)hipMemsetAsync(deg, 0, N_NODES * 4, stream);

    // weight conversion (transposed to [N][K] bf16)
    for (int l = 0; l < 3; ++l) {
        k_convT<<<64, 256, 0, stream>>>(gws[l], wT[2 * l],     128, 128);
        k_convT<<<64, 256, 0, stream>>>(gwn[l], wT[2 * l + 1], 128, 128);
    }
    k_convT<<<64, 256, 0, stream>>>(dw1,             w1aT, 128, 128);
    k_convT<<<64, 256, 0, stream>>>(dw1 + 128 * 128, w1bT, 128, 128);
    k_convX<<<(MPAD * 64 + 255) / 256, 256, 0, stream>>>((const f32x2*)x, (u32*)h0);

    // CSR build
    k_hist<<<(N_EDGES + 255) / 256, 256, 0, stream>>>(edge_row, deg);
    k_scan1<<<98, 1024, 0, stream>>>(deg, incl, bsums);
    k_scan2<<<1, 128, 0, stream>>>(bsums, 98);
    k_scan3<<<(N_NODES + 255) / 256, 256, 0, stream>>>(incl, bsums, rowptr, cursor);
    k_scatter<<<(N_EDGES + 255) / 256, 256, 0, stream>>>(edge_row, edge_col, edge_w, cursor, cce);

    const int GB = MPAD / 64;                  // 1563
    const int AB = 8 * ((N_NODES + 31) / 32);  // 8 chunks * 3125 nodeblocks

    // layer 1: x -> h1
    k_gemm_pair<<<GB, 256, 0, stream>>>(h0, wT[0], wT[1], hsb, supc);
    k_aggregate_c<<<AB, 256, 0, stream>>>((const u32*)supc, (const u32*)hsb, rowptr, cce,
                                          (const f32x2*)gb[0], (u32*)h1, nullptr, 1);
    // layer 2: h1 -> h0
    k_gemm_pair<<<GB, 256, 0, stream>>>(h1, wT[2], wT[3], hsb, supc);
    k_aggregate_c<<<AB, 256, 0, stream>>>((const u32*)supc, (const u32*)hsb, rowptr, cce,
                                          (const f32x2*)gb[1], (u32*)h0, nullptr, 1);
    // layer 3: h0 -> h1 (=z bf16) + z f32 to d_out
    k_gemm_pair<<<GB, 256, 0, stream>>>(h0, wT[4], wT[5], hsb, supc);
    k_aggregate_c<<<AB, 256, 0, stream>>>((const u32*)supc, (const u32*)hsb, rowptr, cce,
                                          (const f32x2*)gb[2], (u32*)h1, (f32x2*)out_z, 0);
    // decoder precompute: U = z@W1a + b1, V = z@W1b  (into the freed hsb region)
    k_gemm_uv<<<GB, 256, 0, stream>>>(h1, w1aT, w1bT, db1, U, V);
    // pair decoder
    k_pairdec<<<(N_PAIRS * 4 + 255) / 256, 256, 0, stream>>>(U, V, x_idx, y_idx, dw2, db2, out_p);
}